// Round 11
// baseline (224.066 us; speedup 1.0000x reference)
//
#include <hip/hip_runtime.h>

typedef unsigned short u16;
typedef short s16x8 __attribute__((ext_vector_type(8)));
typedef short s16x4 __attribute__((ext_vector_type(4)));
typedef float f32x4 __attribute__((ext_vector_type(4)));

#define MFMA_BF16(A,B,C) __builtin_amdgcn_mfma_f32_16x16x32_bf16(A,B,C,0,0,0)

#if defined(__has_builtin)
#if __has_builtin(__builtin_amdgcn_mfma_f32_16x16x16bf16_1k)
#define HAVE_MFMA16 1
#define MFMA16(A,B,C) __builtin_amdgcn_mfma_f32_16x16x16bf16_1k(A,B,C,0,0,0)
#endif
#endif

static constexpr int DMODEL = 1024;
static constexpr int SEQn   = 2048;
static constexpr int BATCH  = 2;
static constexpr int NH     = 16;
static constexpr int DKn    = 64;
static constexpr int ROWST  = BATCH*DMODEL;   // 2048: row stride of [S,B,1024]
// softmax scale folded into Q projection: 0.125 * log2(e)
static constexpr float QSCALE = 0.18033688011112042f;

__device__ __forceinline__ u16 f2bf(float f) {
    unsigned u = __builtin_bit_cast(unsigned, f);
    u += 0x7FFFu + ((u >> 16) & 1u);       // RNE
    return (u16)(u >> 16);
}

#if defined(__has_builtin)
#if __has_builtin(__builtin_amdgcn_cvt_pk_bf16_f32)
#define HAVE_PKBF16 1
#endif
#endif
#ifdef HAVE_PKBF16
typedef __bf16 bf16x2 __attribute__((ext_vector_type(2)));
__device__ __forceinline__ unsigned pk2bf(float a, float b) {
    bf16x2 t = __builtin_amdgcn_cvt_pk_bf16_f32(a, b);
    return __builtin_bit_cast(unsigned, t);
}
#else
__device__ __forceinline__ unsigned pk2bf(float a, float b) {
    return (unsigned)f2bf(a) | ((unsigned)f2bf(b) << 16);
}
#endif

__device__ __forceinline__ void gld_lds16(const u16* g, u16* l) {
    __builtin_amdgcn_global_load_lds(
        (const __attribute__((address_space(1))) void*)g,
        (__attribute__((address_space(3))) void*)l,
        16, 0, 0);
}

// ---------------------------------------------------------------------------
// fp32 -> bf16 conversion pre-pass (all 7 tensors). R8/R9 proved fused-cvt
// is structurally slower (reg-staging loses ~16us vs gld_lds even with
// traffic fixed) — conversion stays a pre-pass. ~BW floor (~16us).
// ---------------------------------------------------------------------------
__global__ void cvt_bf16(const float* __restrict__ q, const float* __restrict__ k,
                         const float* __restrict__ v, const float* __restrict__ wq,
                         const float* __restrict__ wk, const float* __restrict__ wv,
                         const float* __restrict__ wo,
                         u16* __restrict__ qb, u16* __restrict__ kb, u16* __restrict__ vb,
                         u16* __restrict__ wqb, u16* __restrict__ wkb, u16* __restrict__ wvb,
                         u16* __restrict__ wob)
{
    const int z = blockIdx.z;
    const float* S; u16* D; size_t n;
    switch (z) {
        case 0: S = q;  D = qb;  n = 4194304; break;
        case 1: S = k;  D = kb;  n = 4194304; break;
        case 2: S = v;  D = vb;  n = 4194304; break;
        case 3: S = wq; D = wqb; n = 1048576; break;
        case 4: S = wk; D = wkb; n = 1048576; break;
        case 5: S = wv; D = wvb; n = 1048576; break;
        default: S = wo; D = wob; n = 1048576; break;
    }
    const size_t i = ((size_t)blockIdx.x * 256 + threadIdx.x) * 8;
    if (i >= n) return;
    float4 a = *(const float4*)(S + i);
    float4 b = *(const float4*)(S + i + 4);
    uint4 pk;
    pk.x = pk2bf(a.x, a.y); pk.y = pk2bf(a.z, a.w);
    pk.z = pk2bf(b.x, b.y); pk.w = pk2bf(b.z, b.w);
    *(uint4*)(D + i) = pk;
}

// ---------------------------------------------------------------------------
// QKV projection GEMM (R10 — frozen at best: counted-vmcnt 3-slot pipeline +
// XCD panel clustering). 128x128 tile, BK=32, 768 blocks = 3/CU.
// ---------------------------------------------------------------------------
__global__ __launch_bounds__(256, 3)
void gemm_qkv(const u16* __restrict__ A0, const u16* __restrict__ A1, const u16* __restrict__ A2,
              const u16* __restrict__ W0, const u16* __restrict__ W1, const u16* __restrict__ W2,
              const float* __restrict__ B0, const float* __restrict__ B1, const float* __restrict__ B2,
              u16* __restrict__ O0, u16* __restrict__ O1, u16* __restrict__ O2)
{
    // XCD panel clustering: 768 = 8 xcd x (12 panels x 8 ntiles)
    const int bid = blockIdx.x;
    const int xcd = bid & 7, loc = bid >> 3;
    const int pid = xcd * 12 + (loc >> 3);
    const int nt  = loc & 7;
    const int z = pid >> 5, mt = pid & 31;
    const int m0 = mt * 128, n0 = nt * 128;

    const u16* A; const u16* W; const float* bias; u16* Out;
    if (z == 0)      { A = A0; W = W0; bias = B0; Out = O0; }
    else if (z == 1) { A = A1; W = W1; bias = B1; Out = O1; }
    else             { A = A2; W = W2; bias = B2; Out = O2; }

    __shared__ alignas(16) u16 SH[24576];   // 3 slots x (A 4096 + B 4096)

    const int tid  = threadIdx.x;
    const int wave = tid >> 6, lane = tid & 63;
    const int quad = lane >> 4, col = lane & 15;
    const int wm = wave & 1, wn = wave >> 1;

    f32x4 acc[4][4];
#pragma unroll
    for (int i = 0; i < 4; ++i)
#pragma unroll
        for (int j = 0; j < 4; ++j) acc[i][j] = f32x4{0.f,0.f,0.f,0.f};

    auto stageT = [&](int t) {
        const int slot = t % 3;
        const int k0 = t * 32;
        u16* Ad = SH + slot*4096;
        u16* Bd = SH + 12288 + slot*4096;
#pragma unroll
        for (int i = 0; i < 2; ++i) {
            const int idx = i*256 + wave*64 + lane;      // chunk id 0..511
            const int row = idx >> 2;
            const int g = (idx & 3) ^ ((row >> 1) & 3);  // source k-chunk
            gld_lds16(A + (size_t)(m0 + row)*DMODEL + k0 + g*8, Ad + (i*256 + wave*64)*8);
            gld_lds16(W + (size_t)(n0 + row)*DMODEL + k0 + g*8, Bd + (i*256 + wave*64)*8);
        }
    };
    auto compute = [&](int slot) {
        const u16* As_ = SH + slot*4096;
        const u16* Bs_ = SH + 12288 + slot*4096;
        s16x8 af[4], bfr[4];
#pragma unroll
        for (int t4 = 0; t4 < 4; ++t4) {
            const int ra = wm*64 + t4*16 + col;
            af[t4]  = *(const s16x8*)&As_[ra*32 + ((quad ^ ((ra >> 1) & 3))*8)];
            const int rb = wn*64 + t4*16 + col;
            bfr[t4] = *(const s16x8*)&Bs_[rb*32 + ((quad ^ ((rb >> 1) & 3))*8)];
        }
        __builtin_amdgcn_s_setprio(1);
#pragma unroll
        for (int i = 0; i < 4; ++i)
#pragma unroll
            for (int j = 0; j < 4; ++j)
                acc[i][j] = MFMA_BF16(af[i], bfr[j], acc[i][j]);
        __builtin_amdgcn_s_setprio(0);
    };

    stageT(0); stageT(1);                     // 8 glds/lane in flight

    for (int t = 0; t < 31; ++t) {            // K = 32 tiles
        asm volatile("s_waitcnt vmcnt(4)" ::: "memory");   // tile t landed
        __builtin_amdgcn_s_barrier();
        asm volatile("" ::: "memory");
        if (t < 30) stageT(t + 2);            // slot (t+2)%3: readers done pre-barrier
        compute(t % 3);
    }
    asm volatile("s_waitcnt vmcnt(0)" ::: "memory");       // tile 31 landed
    __builtin_amdgcn_s_barrier();
    asm volatile("" ::: "memory");
    compute(31 % 3);

    float bv[4];
#pragma unroll
    for (int j = 0; j < 4; ++j) bv[j] = bias[n0 + wn*64 + j*16 + col];

    const float osc = (z == 0) ? QSCALE : 1.f;   // fold softmax scale into Q
    const int SST = (z == 2) ? 129 : 128;        // epilogue tile row stride
    __syncthreads();   // all waves' K-loop LDS reads done; reuse SH
#pragma unroll
    for (int i = 0; i < 4; ++i)
#pragma unroll
        for (int j = 0; j < 4; ++j) {
            const int nl = wn*64 + j*16 + col;
#pragma unroll
            for (int r = 0; r < 4; ++r) {
                const int ml = wm*64 + i*16 + quad*4 + r;
                SH[ml*SST + nl] = f2bf((acc[i][j][r] + bv[j])*osc);
            }
        }
    __syncthreads();
    if (z < 2) {
        // [S,B,1024] row-major == [m][n]: 2048 16B chunks, fully coalesced
#pragma unroll
        for (int t = 0; t < 8; ++t) {
            const int c = t*256 + tid;
            const int ml = c >> 4, n8 = (c & 15)*8;
            uint4 x = *(const uint4*)&SH[ml*128 + n8];
            *(uint4*)(Out + (size_t)(m0 + ml)*DMODEL + n0 + n8) = x;
        }
    } else {
        // V -> [B,H,64,S]: lanes 0..7 take the 8 s-chunks of one (b,h,d) row
        const int s0 = m0 >> 1;
#pragma unroll
        for (int t = 0; t < 8; ++t) {
            const int c = t*256 + tid;
            const int sc = c & 7;              // s-chunk (8 s each)
            const int nl = (c >> 3) & 127;     // local head-dim index
            const int bb = c >> 10;            // batch
            u16 e[8];
#pragma unroll
            for (int j = 0; j < 8; ++j)
                e[j] = SH[((sc*8 + j)*2 + bb)*129 + nl];
            uint4 x; __builtin_memcpy(&x, e, 16);
            const int ng = n0 + nl, hh = ng >> 6, dd = ng & 63;
            *(uint4*)(Out + (((size_t)bb*NH + hh)*DKn + dd)*SEQn + s0 + sc*8) = x;
        }
    }
}

// ---------------------------------------------------------------------------
// Final-projection GEMM — R11: 8 WAVES per block (512 thr), same 128x128
// tile / BK=32 / 3-slot counted-vmcnt rotation / XCD clustering.
// R10 theory: fin ran 256 blocks x 4 waves = 1 wave/SIMD — a counted-vmcnt
// pipeline with zero co-resident waves has every stall exposed. 8 waves/block
// -> 2 waves/SIMD; per-wave output acc[4][2] (wn quarters N); staging is
// exactly 1 A-gld + 1 W-gld per lane per tile (uniform vmcnt: steady
// vmcnt(2), tail vmcnt(0)). Slot rotation & swizzle identical to gemm_qkv.
// ---------------------------------------------------------------------------
__global__ __launch_bounds__(512, 1)
void gemm_fin(const u16* __restrict__ A, const u16* __restrict__ W,
              const float* __restrict__ bias, float* __restrict__ Outv)
{
    // XCD clustering: 256 = 8 xcd x (4 panels x 8 ntiles)
    const int bid = blockIdx.x;
    const int xcd = bid & 7, loc = bid >> 3;
    const int pid = xcd * 4 + (loc >> 3);
    const int nt  = loc & 7;
    const int m0 = pid * 128, n0 = nt * 128;

    __shared__ alignas(16) u16 SH[24576];   // 3 slots x (A 4096 + B 4096)

    const int tid  = threadIdx.x;
    const int wave = tid >> 6, lane = tid & 63;
    const int quad = lane >> 4, col = lane & 15;
    const int wm = wave & 1, wn = wave >> 1;   // wm: M half (64), wn: N quarter (32)

    f32x4 acc[4][2];
#pragma unroll
    for (int i = 0; i < 4; ++i)
#pragma unroll
        for (int j = 0; j < 2; ++j) acc[i][j] = f32x4{0.f,0.f,0.f,0.f};

    // stage tile t: 512 A-chunks + 512 W-chunks over 512 lanes (1+1 each)
    auto stageT = [&](int t) {
        const int slot = t % 3;
        const int k0 = t * 32;
        u16* Ad = SH + slot*4096;
        u16* Bd = SH + 12288 + slot*4096;
        const int idx = wave*64 + lane;          // chunk id 0..511
        const int row = idx >> 2;
        const int g = (idx & 3) ^ ((row >> 1) & 3);
        gld_lds16(A + (size_t)(m0 + row)*DMODEL + k0 + g*8, Ad + wave*512);
        gld_lds16(W + (size_t)(n0 + row)*DMODEL + k0 + g*8, Bd + wave*512);
    };
    auto compute = [&](int slot) {
        const u16* As_ = SH + slot*4096;
        const u16* Bs_ = SH + 12288 + slot*4096;
        s16x8 af[4], bfr[2];
#pragma unroll
        for (int fj = 0; fj < 2; ++fj) {
            const int rb = wn*32 + fj*16 + col;
            bfr[fj] = *(const s16x8*)&Bs_[rb*32 + ((quad ^ ((rb >> 1) & 3))*8)];
        }
#pragma unroll
        for (int fi = 0; fi < 4; ++fi) {
            const int ra = wm*64 + fi*16 + col;
            af[fi] = *(const s16x8*)&As_[ra*32 + ((quad ^ ((ra >> 1) & 3))*8)];
        }
        __builtin_amdgcn_s_setprio(1);
#pragma unroll
        for (int fi = 0; fi < 4; ++fi)
#pragma unroll
            for (int fj = 0; fj < 2; ++fj)
                acc[fi][fj] = MFMA_BF16(af[fi], bfr[fj], acc[fi][fj]);
        __builtin_amdgcn_s_setprio(0);
    };

    stageT(0); stageT(1);                     // 4 glds/lane in flight

    for (int t = 0; t < 31; ++t) {
        asm volatile("s_waitcnt vmcnt(2)" ::: "memory");   // tile t landed
        __builtin_amdgcn_s_barrier();
        asm volatile("" ::: "memory");
        if (t < 30) stageT(t + 2);            // slot (t+2)%3: readers done pre-barrier
        compute(t % 3);
    }
    asm volatile("s_waitcnt vmcnt(0)" ::: "memory");       // tile 31 landed
    __builtin_amdgcn_s_barrier();
    asm volatile("" ::: "memory");
    compute(31 % 3);

    float bv[2];
#pragma unroll
    for (int fj = 0; fj < 2; ++fj) bv[fj] = bias[n0 + wn*32 + fj*16 + col];
#pragma unroll
    for (int fi = 0; fi < 4; ++fi)
#pragma unroll
        for (int fj = 0; fj < 2; ++fj) {
            const int n = n0 + wn*32 + fj*16 + col;
#pragma unroll
            for (int r = 0; r < 4; ++r) {
                const int m = m0 + wm*64 + fi*16 + quad*4 + r;
                Outv[(size_t)m*DMODEL + n] = acc[fi][fj][r] + bv[fj];
            }
        }
}

// ---------------------------------------------------------------------------
// Flash attention v4 (FROZEN — best measured: 59.2us; R1-R6 tried wider
// q/wave, dbuf, 2-wave blocks, key-split, and de-staging: all >=5us worse;
// de-staging (R6) was 6x worse — LDS staging IS the coalescing layer for
// the 4KB-stride K fragment reads). No-max streaming softmax; Q pre-scaled
// -> p = exp2(s). Denominator via ones-MFMA. 64-row Q tile, 4 waves, 32KB
// LDS, 4 blocks/CU = 16 waves/CU.
// ---------------------------------------------------------------------------
__global__ __launch_bounds__(256, 4)
void attn_fwd(const u16* __restrict__ Q, const u16* __restrict__ K,
              const u16* __restrict__ Vt, u16* __restrict__ O)
{
    __shared__ alignas(16) u16 Ks[128*64];     // [key][d], swizzle ^(key&7)
    __shared__ alignas(16) u16 Vs[64*128];     // [d][key], swizzle ^(d&15)

    const int qt = blockIdx.x, bh = blockIdx.y;
    const int b = bh >> 4, h = bh & 15;
    const int tid = threadIdx.x;
    const int wave = tid >> 6, lane = tid & 63;
    const int quad = lane >> 4, col = lane & 15;

    const u16* Qh = Q + b*DMODEL + h*DKn;       // + s*ROWST + d
    const u16* Kh = K + b*DMODEL + h*DKn;
    const u16* Vh = Vt + (size_t)bh*DKn*SEQn;

    const int q0 = qt*64 + wave*16;
    s16x8 qf[2];   // B-frags: lane holds Q[q0+col][ks*32+quad*8 .. +7]
#pragma unroll
    for (int ks = 0; ks < 2; ++ks)
        qf[ks] = *(const s16x8*)(Qh + (size_t)(q0 + col)*ROWST + ks*32 + quad*8);

    const short ONEBF = (short)0x3F80;          // bf16 1.0
    const s16x4 ones = {ONEBF, ONEBF, ONEBF, ONEBF};

    f32x4 o[4];                    // O^T[d=dt*16+quad*4+r][q=col]
    f32x4 lacc = f32x4{0.f,0.f,0.f,0.f};   // denominator via ones-MFMA
#pragma unroll
    for (int dt = 0; dt < 4; ++dt) o[dt] = f32x4{0.f,0.f,0.f,0.f};

    for (int kt = 0; kt < SEQn/128; ++kt) {
        __syncthreads();   // prev iteration's LDS readers done
#pragma unroll
        for (int i = 0; i < 4; ++i) {
            {   // K tile: 128 rows x 64 d = 1024 16B chunks
                const int chunk = (i*4 + wave)*64 + lane;
                const int row = chunk >> 3;
                const int kk = ((chunk & 7) ^ (row & 7))*8;
                gld_lds16(Kh + (size_t)(kt*128 + row)*ROWST + kk, &Ks[(i*4 + wave)*512]);
            }
            {   // V^T tile: 64 rows x 128 k = 1024 16B chunks
                const int chunk = (i*4 + wave)*64 + lane;
                const int d = chunk >> 4;
                const int kk = ((chunk & 15) ^ (d & 15))*8;
                gld_lds16(Vh + (size_t)d*SEQn + kt*128 + kk, &Vs[(i*4 + wave)*512]);
            }
        }
        __syncthreads();

        // S^T = K Q^T : sfr[nt] holds S^T[key=nt*16+quad*4+r][q=col]
        f32x4 sfr[8];
#pragma unroll
        for (int nt = 0; nt < 8; ++nt) sfr[nt] = f32x4{0.f,0.f,0.f,0.f};
#pragma unroll
        for (int ks = 0; ks < 2; ++ks) {
            s16x8 kf[8];
#pragma unroll
            for (int nt = 0; nt < 8; ++nt) {
                const int key = nt*16 + col;
                kf[nt] = *(const s16x8*)&Ks[key*64 + (((ks*4 + quad) ^ (key & 7))*8)];
            }
#pragma unroll
            for (int nt = 0; nt < 8; ++nt)
                sfr[nt] = MFMA_BF16(kf[nt], qf[ks], sfr[nt]);   // A=K rows, B=Q rows
        }

        // p = exp2(s) (scale pre-folded into Q); pack to bf16 B-frags
        s16x4 pk[8];   // P^T[key=nt*16+quad*4+j][q=col] as bf16x4
#pragma unroll
        for (int nt = 0; nt < 8; ++nt) {
            float p0 = __builtin_amdgcn_exp2f(sfr[nt][0]);
            float p1 = __builtin_amdgcn_exp2f(sfr[nt][1]);
            float p2 = __builtin_amdgcn_exp2f(sfr[nt][2]);
            float p3 = __builtin_amdgcn_exp2f(sfr[nt][3]);
            unsigned w[2] = { pk2bf(p0, p1), pk2bf(p2, p3) };
            __builtin_memcpy(&pk[nt], w, 8);
        }

#ifdef HAVE_MFMA16
        // O^T += V^T P^T and lacc += ones P^T (denominator, cross-quad free)
#pragma unroll
        for (int c = 0; c < 8; ++c) {
            lacc = MFMA16(ones, pk[c], lacc);
#pragma unroll
            for (int dt = 0; dt < 4; ++dt) {
                const int d = dt*16 + col;
                const s16x4 vfr = *(const s16x4*)&Vs[d*128 + (((c*2 + (quad>>1)) ^ (d & 15))*8) + (quad & 1)*4];
                o[dt] = MFMA16(vfr, pk[c], o[dt]);
            }
        }
#else
        // Fallback: K=32 MFMA; B-frags assembled cross-quad via ds_bpermute
        const int a0 = (32*(quad & 1) + col)*4;
        const s16x8 ones8 = {ONEBF,ONEBF,ONEBF,ONEBF,ONEBF,ONEBF,ONEBF,ONEBF};
#pragma unroll
        for (int ksp = 0; ksp < 4; ++ksp) {
            int pA[2], pB[2];
            __builtin_memcpy(pA, &pk[ksp*2], 8);
            __builtin_memcpy(pB, &pk[ksp*2 + 1], 8);
            int w[4];
#pragma unroll
            for (int hh = 0; hh < 2; ++hh) {
                const int ad = a0 + hh*64;
                const int xA0 = __builtin_amdgcn_ds_bpermute(ad, pA[0]);
                const int xA1 = __builtin_amdgcn_ds_bpermute(ad, pA[1]);
                const int xB0 = __builtin_amdgcn_ds_bpermute(ad, pB[0]);
                const int xB1 = __builtin_amdgcn_ds_bpermute(ad, pB[1]);
                w[hh*2]     = (quad >= 2) ? xB0 : xA0;
                w[hh*2 + 1] = (quad >= 2) ? xB1 : xA1;
            }
            s16x8 pfr; __builtin_memcpy(&pfr, w, 16);
            lacc = MFMA_BF16(ones8, pfr, lacc);
#pragma unroll
            for (int dt = 0; dt < 4; ++dt) {
                const int d = dt*16 + col;
                const s16x8 vfr = *(const s16x8*)&Vs[d*128 + (((ksp*4 + quad) ^ (d & 15))*8)];
                o[dt] = MFMA_BF16(vfr, pfr, o[dt]);
            }
        }
#endif
    }

    // epilogue: lane holds O^T[d=dt*16+quad*4+r][q=col]; packed 8B stores
    const float inv = 1.f / lacc[0];
    const int srow = q0 + col;
#pragma unroll
    for (int dt = 0; dt < 4; ++dt) {
        uint2 pko;
        pko.x = pk2bf(o[dt][0]*inv, o[dt][1]*inv);
        pko.y = pk2bf(o[dt][2]*inv, o[dt][3]*inv);
        *(uint2*)(O + ((size_t)srow*BATCH + b)*DMODEL + h*DKn + dt*16 + quad*4) = pko;
    }
}

// ---------------------------------------------------------------------------
extern "C" void kernel_launch(void* const* d_in, const int* in_sizes, int n_in,
                              void* d_out, int out_size, void* d_ws, size_t ws_size,
                              hipStream_t stream)
{
    const float* q  = (const float*)d_in[0];
    const float* k  = (const float*)d_in[1];
    const float* v  = (const float*)d_in[2];
    const float* Wq = (const float*)d_in[3];
    const float* bq = (const float*)d_in[4];
    const float* Wk = (const float*)d_in[5];
    const float* bk = (const float*)d_in[6];
    const float* Wv = (const float*)d_in[7];
    const float* bv = (const float*)d_in[8];
    const float* Wo = (const float*)d_in[9];
    const float* bo = (const float*)d_in[10];
    float* out = (float*)d_out;

    const size_t N = (size_t)SEQn * BATCH * DMODEL;   // 4,194,304 elements
    const size_t NW = (size_t)DMODEL * DMODEL;        // 1,048,576
    u16* qb  = (u16*)d_ws;       // bf16 inputs
    u16* kb  = qb + N;
    u16* vb  = kb + N;
    u16* wqb = vb + N;
    u16* wkb = wqb + NW;
    u16* wvb = wkb + NW;
    u16* wob = wvb + NW;
    u16* Qw  = wob + NW;         // [S,B,1024], pre-scaled by QSCALE
    u16* Kw  = Qw + N;           // [S,B,1024]
    u16* Vtw = Kw + N;           // [B,H,64,S]
    u16* AO  = qb;               // [S,B,1024]; reuses qb (dead after QKV gemm)
    // ws_size needed: (3N + 4NW + 3N)*2 = 58,720,256 bytes

    // 1) fp32 -> bf16
    cvt_bf16<<<dim3(2048, 1, 7), 256, 0, stream>>>(q, k, v, Wq, Wk, Wv, Wo,
                                                   qb, kb, vb, wqb, wkb, wvb, wob);
    // 2) Q/K/V projections (frozen at R10 best): 768 blocks, XCD-clustered
    gemm_qkv<<<dim3(768), 256, 0, stream>>>(qb, kb, vb, wqb, wkb, wvb,
                                            bq, bk, bv, Qw, Kw, Vtw);
    // 3) attention (v4, frozen): 64 q rows/block, 1024 blocks = 4 blocks/CU
    attn_fwd<<<dim3(32, 32), 256, 0, stream>>>(Qw, Kw, Vtw, AO);
    // 4) output projection: 8-wave blocks (2 waves/SIMD), XCD-clustered
    gemm_fin<<<dim3(256), 512, 0, stream>>>(AO, wob, bo, out);
}

// Round 12
// 218.401 us; speedup vs baseline: 1.0259x; 1.0259x over previous
//
#include <hip/hip_runtime.h>

typedef unsigned short u16;
typedef short s16x8 __attribute__((ext_vector_type(8)));
typedef short s16x4 __attribute__((ext_vector_type(4)));
typedef float f32x4 __attribute__((ext_vector_type(4)));

#define MFMA_BF16(A,B,C) __builtin_amdgcn_mfma_f32_16x16x32_bf16(A,B,C,0,0,0)

#if defined(__has_builtin)
#if __has_builtin(__builtin_amdgcn_mfma_f32_16x16x16bf16_1k)
#define HAVE_MFMA16 1
#define MFMA16(A,B,C) __builtin_amdgcn_mfma_f32_16x16x16bf16_1k(A,B,C,0,0,0)
#endif
#endif

static constexpr int DMODEL = 1024;
static constexpr int SEQn   = 2048;
static constexpr int BATCH  = 2;
static constexpr int NH     = 16;
static constexpr int DKn    = 64;
static constexpr int ROWST  = BATCH*DMODEL;   // 2048: row stride of [S,B,1024]
// softmax scale folded into Q projection: 0.125 * log2(e)
static constexpr float QSCALE = 0.18033688011112042f;

__device__ __forceinline__ u16 f2bf(float f) {
    unsigned u = __builtin_bit_cast(unsigned, f);
    u += 0x7FFFu + ((u >> 16) & 1u);       // RNE
    return (u16)(u >> 16);
}

#if defined(__has_builtin)
#if __has_builtin(__builtin_amdgcn_cvt_pk_bf16_f32)
#define HAVE_PKBF16 1
#endif
#endif
#ifdef HAVE_PKBF16
typedef __bf16 bf16x2 __attribute__((ext_vector_type(2)));
__device__ __forceinline__ unsigned pk2bf(float a, float b) {
    bf16x2 t = __builtin_amdgcn_cvt_pk_bf16_f32(a, b);
    return __builtin_bit_cast(unsigned, t);
}
#else
__device__ __forceinline__ unsigned pk2bf(float a, float b) {
    return (unsigned)f2bf(a) | ((unsigned)f2bf(b) << 16);
}
#endif

__device__ __forceinline__ void gld_lds16(const u16* g, u16* l) {
    __builtin_amdgcn_global_load_lds(
        (const __attribute__((address_space(1))) void*)g,
        (__attribute__((address_space(3))) void*)l,
        16, 0, 0);
}

// ---------------------------------------------------------------------------
// fp32 -> bf16 conversion pre-pass (R7 form: all 7 tensors). R8/R9 proved the
// fused-cvt alternative is structurally slower (reg-staging loses ~16us vs
// gld_lds staging even with traffic fixed) — conversion stays a pre-pass.
// ---------------------------------------------------------------------------
__global__ void cvt_bf16(const float* __restrict__ q, const float* __restrict__ k,
                         const float* __restrict__ v, const float* __restrict__ wq,
                         const float* __restrict__ wk, const float* __restrict__ wv,
                         const float* __restrict__ wo,
                         u16* __restrict__ qb, u16* __restrict__ kb, u16* __restrict__ vb,
                         u16* __restrict__ wqb, u16* __restrict__ wkb, u16* __restrict__ wvb,
                         u16* __restrict__ wob)
{
    const int z = blockIdx.z;
    const float* S; u16* D; size_t n;
    switch (z) {
        case 0: S = q;  D = qb;  n = 4194304; break;
        case 1: S = k;  D = kb;  n = 4194304; break;
        case 2: S = v;  D = vb;  n = 4194304; break;
        case 3: S = wq; D = wqb; n = 1048576; break;
        case 4: S = wk; D = wkb; n = 1048576; break;
        case 5: S = wv; D = wvb; n = 1048576; break;
        default: S = wo; D = wob; n = 1048576; break;
    }
    const size_t i = ((size_t)blockIdx.x * 256 + threadIdx.x) * 8;
    if (i >= n) return;
    float4 a = *(const float4*)(S + i);
    float4 b = *(const float4*)(S + i + 4);
    uint4 pk;
    pk.x = pk2bf(a.x, a.y); pk.y = pk2bf(a.z, a.w);
    pk.z = pk2bf(b.x, b.y); pk.w = pk2bf(b.z, b.w);
    *(uint4*)(D + i) = pk;
}

// ---------------------------------------------------------------------------
// Pipelined GEMM (R7 structure, race-proven) + R10: XCD panel clustering.
// 128x128 tile, BK=32, 3-slot LDS rotation (48KB -> 3 blocks/CU), counted
// vmcnt(4) steady state (next tile's loads stay in flight across the
// barrier — never drained in-loop), tail peels vmcnt(0).
// Bijective decode so the 8 blocks sharing an A-panel land on ONE XCD
// (bid%8): panel enters that L2 once.
//   !FINAL: 768 = 8 xcd x 12 panels x 8 ntiles; pid=(z,mt)
//   FINAL : 256 = 8 xcd x 4 panels x 8 ntiles; z=0
// FINAL=true : direct fp32 [M][1024] stores.
// FINAL=false: LDS-repack epilogue; z=0 scaled by QSCALE;
//   z=0/1 -> bf16 [S,B,1024]; z==2 -> bf16 d-major [B,H,64,S] (stride 129).
// R11 NOTE: 8-wave fin variant tried and regressed (+8us; 512-thr 1-block/CU
// halves work/wave at same barrier count) — 4-wave 256-thr form is final.
// ---------------------------------------------------------------------------
template<bool FINAL>
__global__ __launch_bounds__(256, 3)
void gemm_p(const u16* __restrict__ A0, const u16* __restrict__ A1, const u16* __restrict__ A2,
            const u16* __restrict__ W0, const u16* __restrict__ W1, const u16* __restrict__ W2,
            const float* __restrict__ B0, const float* __restrict__ B1, const float* __restrict__ B2,
            void* __restrict__ O0, void* __restrict__ O1, void* __restrict__ O2)
{
    // ---- XCD panel clustering decode (bijections validated in R9) ----
    const int bid = blockIdx.x;
    const int xcd = bid & 7, loc = bid >> 3;
    int z, mt, nt;
    if (FINAL) {                       // 256 = 8 x (4 panels x 8 ntiles)
        const int pid = xcd * 4 + (loc >> 3);
        nt = loc & 7; z = 0; mt = pid;
    } else {                           // 768 = 8 x (12 panels x 8 ntiles)
        const int pid = xcd * 12 + (loc >> 3);
        nt = loc & 7; z = pid >> 5; mt = pid & 31;
    }
    const int m0 = mt * 128, n0 = nt * 128;

    const u16* A; const u16* W; const float* bias; void* Outv;
    if (z == 0)      { A = A0; W = W0; bias = B0; Outv = O0; }
    else if (z == 1) { A = A1; W = W1; bias = B1; Outv = O1; }
    else             { A = A2; W = W2; bias = B2; Outv = O2; }

    // 3 slots x (A 4096 u16 + B 4096 u16) = 48 KiB; epilogue reuses as repack.
    __shared__ alignas(16) u16 SH[24576];

    const int tid  = threadIdx.x;
    const int wave = tid >> 6, lane = tid & 63;
    const int quad = lane >> 4, col = lane & 15;
    const int wm = wave & 1, wn = wave >> 1;

    f32x4 acc[4][4];
#pragma unroll
    for (int i = 0; i < 4; ++i)
#pragma unroll
        for (int j = 0; j < 4; ++j) acc[i][j] = f32x4{0.f,0.f,0.f,0.f};

    // stage K-tile t: A rows m0..+128, W rows n0..+128, k = t*32..+32.
    auto stageT = [&](int t) {
        const int slot = t % 3;
        const int k0 = t * 32;
        u16* Ad = SH + slot*4096;
        u16* Bd = SH + 12288 + slot*4096;
#pragma unroll
        for (int i = 0; i < 2; ++i) {
            const int idx = i*256 + wave*64 + lane;      // chunk id 0..511
            const int row = idx >> 2;
            const int g = (idx & 3) ^ ((row >> 1) & 3);  // source k-chunk
            gld_lds16(A + (size_t)(m0 + row)*DMODEL + k0 + g*8, Ad + (i*256 + wave*64)*8);
            gld_lds16(W + (size_t)(n0 + row)*DMODEL + k0 + g*8, Bd + (i*256 + wave*64)*8);
        }
    };

    auto compute = [&](int slot) {
        const u16* As_ = SH + slot*4096;
        const u16* Bs_ = SH + 12288 + slot*4096;
        s16x8 af[4], bfr[4];
#pragma unroll
        for (int t4 = 0; t4 < 4; ++t4) {
            const int ra = wm*64 + t4*16 + col;
            af[t4]  = *(const s16x8*)&As_[ra*32 + ((quad ^ ((ra >> 1) & 3))*8)];
            const int rb = wn*64 + t4*16 + col;
            bfr[t4] = *(const s16x8*)&Bs_[rb*32 + ((quad ^ ((rb >> 1) & 3))*8)];
        }
        __builtin_amdgcn_s_setprio(1);
#pragma unroll
        for (int i = 0; i < 4; ++i)
#pragma unroll
            for (int j = 0; j < 4; ++j)
                acc[i][j] = MFMA_BF16(af[i], bfr[j], acc[i][j]);
        __builtin_amdgcn_s_setprio(0);
    };

    stageT(0); stageT(1);                     // 8 glds/lane in flight

    for (int t = 0; t < 31; ++t) {            // K = 1024/32 = 32 tiles
        asm volatile("s_waitcnt vmcnt(4)" ::: "memory");   // tile t landed
        __builtin_amdgcn_s_barrier();
        asm volatile("" ::: "memory");
        if (t < 30) stageT(t + 2);            // slot (t+2)%3: readers done pre-barrier
        compute(t % 3);
    }
    asm volatile("s_waitcnt vmcnt(0)" ::: "memory");       // tile 31 landed
    __builtin_amdgcn_s_barrier();
    asm volatile("" ::: "memory");
    compute(31 % 3);                          // = slot 1

    float bv[4];
#pragma unroll
    for (int j = 0; j < 4; ++j) bv[j] = bias[n0 + wn*64 + j*16 + col];

    if (FINAL) {
#pragma unroll
        for (int i = 0; i < 4; ++i)
#pragma unroll
            for (int j = 0; j < 4; ++j) {
                const int n = n0 + wn*64 + j*16 + col;
#pragma unroll
                for (int r = 0; r < 4; ++r) {
                    const int m = m0 + wm*64 + i*16 + quad*4 + r;
                    ((float*)Outv)[(size_t)m*DMODEL + n] = acc[i][j][r] + bv[j];
                }
            }
    } else {
        const float osc = (z == 0) ? QSCALE : 1.f;   // fold softmax scale into Q
        const int SST = (z == 2) ? 129 : 128;        // epilogue tile row stride
        __syncthreads();   // all waves' K-loop LDS reads done; reuse SH
#pragma unroll
        for (int i = 0; i < 4; ++i)
#pragma unroll
            for (int j = 0; j < 4; ++j) {
                const int nl = wn*64 + j*16 + col;
#pragma unroll
                for (int r = 0; r < 4; ++r) {
                    const int ml = wm*64 + i*16 + quad*4 + r;
                    SH[ml*SST + nl] = f2bf((acc[i][j][r] + bv[j])*osc);
                }
            }
        __syncthreads();
        u16* Out = (u16*)Outv;
        if (z < 2) {
            // [S,B,1024] row-major == [m][n]: 2048 16B chunks, fully coalesced
#pragma unroll
            for (int t = 0; t < 8; ++t) {
                const int c = t*256 + tid;
                const int ml = c >> 4, n8 = (c & 15)*8;
                uint4 x = *(const uint4*)&SH[ml*128 + n8];
                *(uint4*)(Out + (size_t)(m0 + ml)*DMODEL + n0 + n8) = x;
            }
        } else {
            // V -> [B,H,64,S]: lanes 0..7 take the 8 s-chunks of one (b,h,d)
            // row -> 128B contiguous per 8-lane group (full 64B lines).
            const int s0 = m0 >> 1;
#pragma unroll
            for (int t = 0; t < 8; ++t) {
                const int c = t*256 + tid;
                const int sc = c & 7;              // s-chunk (8 s each)
                const int nl = (c >> 3) & 127;     // local head-dim index
                const int bb = c >> 10;            // batch
                u16 e[8];
#pragma unroll
                for (int j = 0; j < 8; ++j)
                    e[j] = SH[((sc*8 + j)*2 + bb)*129 + nl];
                uint4 x; __builtin_memcpy(&x, e, 16);
                const int ng = n0 + nl, hh = ng >> 6, dd = ng & 63;
                *(uint4*)(Out + (((size_t)bb*NH + hh)*DKn + dd)*SEQn + s0 + sc*8) = x;
            }
        }
    }
}

// ---------------------------------------------------------------------------
// Flash attention v4 (FROZEN — best measured: 59.2us; R1-R6 tried wider
// q/wave, dbuf, 2-wave blocks, key-split, and de-staging: all >=5us worse;
// de-staging (R6) was 6x worse — LDS staging IS the coalescing layer for
// the 4KB-stride K fragment reads). No-max streaming softmax; Q pre-scaled
// -> p = exp2(s). Denominator via ones-MFMA. 64-row Q tile, 4 waves, 32KB
// LDS, 4 blocks/CU = 16 waves/CU.
// ---------------------------------------------------------------------------
__global__ __launch_bounds__(256, 4)
void attn_fwd(const u16* __restrict__ Q, const u16* __restrict__ K,
              const u16* __restrict__ Vt, u16* __restrict__ O)
{
    __shared__ alignas(16) u16 Ks[128*64];     // [key][d], swizzle ^(key&7)
    __shared__ alignas(16) u16 Vs[64*128];     // [d][key], swizzle ^(d&15)

    const int qt = blockIdx.x, bh = blockIdx.y;
    const int b = bh >> 4, h = bh & 15;
    const int tid = threadIdx.x;
    const int wave = tid >> 6, lane = tid & 63;
    const int quad = lane >> 4, col = lane & 15;

    const u16* Qh = Q + b*DMODEL + h*DKn;       // + s*ROWST + d
    const u16* Kh = K + b*DMODEL + h*DKn;
    const u16* Vh = Vt + (size_t)bh*DKn*SEQn;

    const int q0 = qt*64 + wave*16;
    s16x8 qf[2];   // B-frags: lane holds Q[q0+col][ks*32+quad*8 .. +7]
#pragma unroll
    for (int ks = 0; ks < 2; ++ks)
        qf[ks] = *(const s16x8*)(Qh + (size_t)(q0 + col)*ROWST + ks*32 + quad*8);

    const short ONEBF = (short)0x3F80;          // bf16 1.0
    const s16x4 ones = {ONEBF, ONEBF, ONEBF, ONEBF};

    f32x4 o[4];                    // O^T[d=dt*16+quad*4+r][q=col]
    f32x4 lacc = f32x4{0.f,0.f,0.f,0.f};   // denominator via ones-MFMA
#pragma unroll
    for (int dt = 0; dt < 4; ++dt) o[dt] = f32x4{0.f,0.f,0.f,0.f};

    for (int kt = 0; kt < SEQn/128; ++kt) {
        __syncthreads();   // prev iteration's LDS readers done
#pragma unroll
        for (int i = 0; i < 4; ++i) {
            {   // K tile: 128 rows x 64 d = 1024 16B chunks
                const int chunk = (i*4 + wave)*64 + lane;
                const int row = chunk >> 3;
                const int kk = ((chunk & 7) ^ (row & 7))*8;
                gld_lds16(Kh + (size_t)(kt*128 + row)*ROWST + kk, &Ks[(i*4 + wave)*512]);
            }
            {   // V^T tile: 64 rows x 128 k = 1024 16B chunks
                const int chunk = (i*4 + wave)*64 + lane;
                const int d = chunk >> 4;
                const int kk = ((chunk & 15) ^ (d & 15))*8;
                gld_lds16(Vh + (size_t)d*SEQn + kt*128 + kk, &Vs[(i*4 + wave)*512]);
            }
        }
        __syncthreads();

        // S^T = K Q^T : sfr[nt] holds S^T[key=nt*16+quad*4+r][q=col]
        f32x4 sfr[8];
#pragma unroll
        for (int nt = 0; nt < 8; ++nt) sfr[nt] = f32x4{0.f,0.f,0.f,0.f};
#pragma unroll
        for (int ks = 0; ks < 2; ++ks) {
            s16x8 kf[8];
#pragma unroll
            for (int nt = 0; nt < 8; ++nt) {
                const int key = nt*16 + col;
                kf[nt] = *(const s16x8*)&Ks[key*64 + (((ks*4 + quad) ^ (key & 7))*8)];
            }
#pragma unroll
            for (int nt = 0; nt < 8; ++nt)
                sfr[nt] = MFMA_BF16(kf[nt], qf[ks], sfr[nt]);   // A=K rows, B=Q rows
        }

        // p = exp2(s) (scale pre-folded into Q); pack to bf16 B-frags
        s16x4 pk[8];   // P^T[key=nt*16+quad*4+j][q=col] as bf16x4
#pragma unroll
        for (int nt = 0; nt < 8; ++nt) {
            float p0 = __builtin_amdgcn_exp2f(sfr[nt][0]);
            float p1 = __builtin_amdgcn_exp2f(sfr[nt][1]);
            float p2 = __builtin_amdgcn_exp2f(sfr[nt][2]);
            float p3 = __builtin_amdgcn_exp2f(sfr[nt][3]);
            unsigned w[2] = { pk2bf(p0, p1), pk2bf(p2, p3) };
            __builtin_memcpy(&pk[nt], w, 8);
        }

#ifdef HAVE_MFMA16
        // O^T += V^T P^T and lacc += ones P^T (denominator, cross-quad free)
#pragma unroll
        for (int c = 0; c < 8; ++c) {
            lacc = MFMA16(ones, pk[c], lacc);
#pragma unroll
            for (int dt = 0; dt < 4; ++dt) {
                const int d = dt*16 + col;
                const s16x4 vfr = *(const s16x4*)&Vs[d*128 + (((c*2 + (quad>>1)) ^ (d & 15))*8) + (quad & 1)*4];
                o[dt] = MFMA16(vfr, pk[c], o[dt]);
            }
        }
#else
        // Fallback: K=32 MFMA; B-frags assembled cross-quad via ds_bpermute
        const int a0 = (32*(quad & 1) + col)*4;
        const s16x8 ones8 = {ONEBF,ONEBF,ONEBF,ONEBF,ONEBF,ONEBF,ONEBF,ONEBF};
#pragma unroll
        for (int ksp = 0; ksp < 4; ++ksp) {
            int pA[2], pB[2];
            __builtin_memcpy(pA, &pk[ksp*2], 8);
            __builtin_memcpy(pB, &pk[ksp*2 + 1], 8);
            int w[4];
#pragma unroll
            for (int hh = 0; hh < 2; ++hh) {
                const int ad = a0 + hh*64;
                const int xA0 = __builtin_amdgcn_ds_bpermute(ad, pA[0]);
                const int xA1 = __builtin_amdgcn_ds_bpermute(ad, pA[1]);
                const int xB0 = __builtin_amdgcn_ds_bpermute(ad, pB[0]);
                const int xB1 = __builtin_amdgcn_ds_bpermute(ad, pB[1]);
                w[hh*2]     = (quad >= 2) ? xB0 : xA0;
                w[hh*2 + 1] = (quad >= 2) ? xB1 : xA1;
            }
            s16x8 pfr; __builtin_memcpy(&pfr, w, 16);
            lacc = MFMA_BF16(ones8, pfr, lacc);
#pragma unroll
            for (int dt = 0; dt < 4; ++dt) {
                const int d = dt*16 + col;
                const s16x8 vfr = *(const s16x8*)&Vs[d*128 + (((ksp*4 + quad) ^ (d & 15))*8)];
                o[dt] = MFMA_BF16(vfr, pfr, o[dt]);
            }
        }
#endif
    }

    // epilogue: lane holds O^T[d=dt*16+quad*4+r][q=col]; packed 8B stores
    const float inv = 1.f / lacc[0];
    const int srow = q0 + col;
#pragma unroll
    for (int dt = 0; dt < 4; ++dt) {
        uint2 pko;
        pko.x = pk2bf(o[dt][0]*inv, o[dt][1]*inv);
        pko.y = pk2bf(o[dt][2]*inv, o[dt][3]*inv);
        *(uint2*)(O + ((size_t)srow*BATCH + b)*DMODEL + h*DKn + dt*16 + quad*4) = pko;
    }
}

// ---------------------------------------------------------------------------
extern "C" void kernel_launch(void* const* d_in, const int* in_sizes, int n_in,
                              void* d_out, int out_size, void* d_ws, size_t ws_size,
                              hipStream_t stream)
{
    const float* q  = (const float*)d_in[0];
    const float* k  = (const float*)d_in[1];
    const float* v  = (const float*)d_in[2];
    const float* Wq = (const float*)d_in[3];
    const float* bq = (const float*)d_in[4];
    const float* Wk = (const float*)d_in[5];
    const float* bk = (const float*)d_in[6];
    const float* Wv = (const float*)d_in[7];
    const float* bv = (const float*)d_in[8];
    const float* Wo = (const float*)d_in[9];
    const float* bo = (const float*)d_in[10];
    float* out = (float*)d_out;

    const size_t N = (size_t)SEQn * BATCH * DMODEL;   // 4,194,304 elements
    const size_t NW = (size_t)DMODEL * DMODEL;        // 1,048,576
    u16* qb  = (u16*)d_ws;       // bf16 inputs
    u16* kb  = qb + N;
    u16* vb  = kb + N;
    u16* wqb = vb + N;
    u16* wkb = wqb + NW;
    u16* wvb = wkb + NW;
    u16* wob = wvb + NW;
    u16* Qw  = wob + NW;         // [S,B,1024], pre-scaled by QSCALE
    u16* Kw  = Qw + N;           // [S,B,1024]
    u16* Vtw = Kw + N;           // [B,H,64,S]
    u16* AO  = qb;               // [S,B,1024]; reuses qb (dead after QKV gemm)
    // ws_size needed: (3N + 4NW + 3N)*2 = 58,720,256 bytes

    // 1) fp32 -> bf16
    cvt_bf16<<<dim3(2048, 1, 7), 256, 0, stream>>>(q, k, v, Wq, Wk, Wv, Wo,
                                                   qb, kb, vb, wqb, wkb, wvb, wob);
    // 2) Q/K/V projections: counted-vmcnt pipeline + XCD clustering (768 blocks)
    gemm_p<false><<<dim3(768), 256, 0, stream>>>(qb, kb, vb, wqb, wkb, wvb,
                                                 bq, bk, bv, Qw, Kw, Vtw);
    // 3) attention (v4, frozen): 64 q rows/block, 1024 blocks = 4 blocks/CU
    attn_fwd<<<dim3(32, 32), 256, 0, stream>>>(Qw, Kw, Vtw, AO);
    // 4) output projection: counted-vmcnt pipeline + XCD clustering (256 blocks)
    gemm_p<true><<<dim3(256), 256, 0, stream>>>(AO, AO, AO, wob, wob, wob,
                                                bo, bo, bo, out, out, out);
}